// Round 13
// baseline (2236.926 us; speedup 1.0000x reference)
//
#include <hip/hip_runtime.h>
#include <cstdint>
#include <cstddef>

typedef unsigned short u16;
typedef unsigned int u32;
typedef unsigned long long u64;
typedef __attribute__((ext_vector_type(8))) short bfrag8;   // 8 bf16 = 4 VGPRs
typedef __attribute__((ext_vector_type(4))) float f32x4;

#define NB 64      // batch
#define NT 512     // timesteps
#define NE 256     // embedding dim
#define NH 512     // hidden dim
#define NBLK 256   // persistent blocks: 4 batch-groups x 64 col-blocks
#define WSTR 408   // wlds per-lane stride in u16

__device__ __forceinline__ float bf2f(u16 b) { return __uint_as_float(((unsigned)b) << 16); }
__device__ __forceinline__ u16 f2bf(float f) {
  unsigned u = __float_as_uint(f);
  u += 0x7fffu + ((u >> 16) & 1u);   // round-to-nearest-even
  return (u16)(u >> 16);
}
__device__ __forceinline__ float fsigm(float x) { return 1.0f / (1.0f + __expf(-x)); }
__device__ __forceinline__ float ftanh(float x) { return 2.0f / (1.0f + __expf(-2.0f * x)) - 1.0f; }

// split fp32 -> (hi, lo) bf16 pair; hi + lo == v to ~2^-18 relative
__device__ __forceinline__ void split1(float v, u16& h, u16& l) {
  h = f2bf(v);
  float r = v - bf2f(h);
  l = f2bf(r);
}
__device__ __forceinline__ void split8(const float* p, bfrag8& hi, bfrag8& lo) {
#pragma unroll
  for (int i = 0; i < 8; ++i) {
    u16 h, l; split1(p[i], h, l);
    hi[i] = (short)h; lo[i] = (short)l;
  }
}

__device__ __forceinline__ void unpack8(uint4 q, float* o) {
  o[0] = __uint_as_float(q.x << 16); o[1] = __uint_as_float(q.x & 0xffff0000u);
  o[2] = __uint_as_float(q.y << 16); o[3] = __uint_as_float(q.y & 0xffff0000u);
  o[4] = __uint_as_float(q.z << 16); o[5] = __uint_as_float(q.z & 0xffff0000u);
  o[6] = __uint_as_float(q.w << 16); o[7] = __uint_as_float(q.w & 0xffff0000u);
}

// ---------------- persistent LSTM: 256 blocks = 4 batch-groups x 64 ----------
// Round-12 base (fused staging, packed slot lines, best persist ~1470us) with
// ONE step-loop change: EARLY-POLL FAST PATH. The slot-line load is issued at
// loop TOP (oldest VMEM -> its wait doesn't touch the emb prefetch); after
// the X MFMAs, if that sample already shows t-1 on all lanes we skip the
// poll loop entirely (ordering: h loads are issued after the check of a
// served slot value, so they are served at MALL after the producers' acked
// stores -- same argument as the normal poll). On a miss we fall into the
// UNCHANGED r12 poll loop. r8's regression is explained by its stale 2-deep
// spin (checked a value one RT old), which this does NOT reproduce.
__global__ __launch_bounds__(256, 1) void lstm_persist(
    const int* __restrict__ words,
    const float* __restrict__ emb,
    const float* __restrict__ Whr, const float* __restrict__ Whf,
    const float* __restrict__ Whg, const float* __restrict__ Who,
    const float* __restrict__ Wir, const float* __restrict__ Wif,
    const float* __restrict__ Wig, const float* __restrict__ Wio,
    const float* __restrict__ bhr, const float* __restrict__ bhf,
    const float* __restrict__ bhg, const float* __restrict__ bho,
    const float* __restrict__ bir, const float* __restrict__ bif,
    const float* __restrict__ big_, const float* __restrict__ bio,
    u64* __restrict__ hbuf,     // [2][4][4][4][4][64] u64 fragment-major
    u16* __restrict__ hs_all,   // [T][B][H] bf16 (attention path, cached)
    float* __restrict__ hlast,  // [B][H] fp32 final h
    u32* __restrict__ slots)    // [4 groups][4 waves][16 words] packed lines
{
  const int G    = blockIdx.x >> 6;         // batch group 0..3
  const int ib   = blockIdx.x & 63;         // col-block 0..63
  const int tid  = threadIdx.x;
  const int lane = tid & 63;
  const int wave = tid >> 6;                // K-slice 0..3
  const int colq = lane & 15;
  const int koff = (lane >> 4) * 8;
  const int arow = 16 * G + colq;           // batch row for A fragments

  __shared__ u16 wlds[2 * 64 * WSTR];       // ~102KB weights (2 col-groups)
  __shared__ float pl[4 * 16 * 34];         // K-partials [w][row][32+pad]
  __shared__ float biasLds[32];

  // ---- fused weight staging: identical image to the old stage_weights ----
  if (wave < 2) {
    const int wg2  = ib * 2 + wave;         // old staging-wg index
    const int gate = colq >> 2;
    const int gu   = wg2 * 4 + (colq & 3);
    const float* wh = (gate == 0) ? Whr : (gate == 1) ? Whf : (gate == 2) ? Whg : Who;
    const float* wi = (gate == 0) ? Wir : (gate == 1) ? Wif : (gate == 2) ? Wig : Wio;
    const float* whp = wh + (size_t)gu * NH + koff;
    const float* wip = wi + (size_t)gu * NE + koff;
    u16* dst = wlds + (size_t)(wave * 64 + lane) * WSTR;
#pragma unroll
    for (int kt = 0; kt < 16; ++kt) {
      bfrag8 hi, lo; split8(whp + kt * 32, hi, lo);
      *(bfrag8*)(dst + kt * 8) = hi;
      *(bfrag8*)(dst + (16 + kt) * 8) = lo;
    }
#pragma unroll
    for (int kt = 0; kt < 8; ++kt) {
      bfrag8 hi, lo; split8(wip + kt * 32, hi, lo);
      *(bfrag8*)(dst + (32 + kt) * 8) = hi;
      *(bfrag8*)(dst + (40 + kt) * 8) = lo;
    }
  }
  if (tid < 32) {
    int wg2 = ib * 2 + (tid >> 4), l = tid & 15;
    int g2 = l >> 2, u2 = l & 3, gu2 = wg2 * 4 + u2;
    const float* bh = (g2 == 0) ? bhr : (g2 == 1) ? bhf : (g2 == 2) ? bhg : bho;
    const float* bi = (g2 == 0) ? bir : (g2 == 1) ? bif : (g2 == 2) ? big_ : bio;
    biasLds[tid] = bh[gu2] + bi[gu2];
  }
  __syncthreads();

  const bool is64 = ((words[1] | words[3] | words[5] | words[7]) == 0);
  const int r_loc = tid >> 3;               // gate-phase row (tid<128)
  const int uo    = tid & 7;                // gate-phase unit offset
  float creg = 0.0f;                        // one cell state per gate thread

  // preamble: emb gather for t=1 (wave w loads its X k-slice only)
  f32x4 xa[2], xb[2];
  {
    int widx = arow * NT + 0;
    int wd = is64 ? words[2 * widx] : words[widx];
    const float* xs = emb + (size_t)wd * NE + wave * 64 + koff;
    xa[0] = *(const f32x4*)(xs);      xb[0] = *(const f32x4*)(xs + 4);
    xa[1] = *(const f32x4*)(xs + 32); xb[1] = *(const f32x4*)(xs + 36);
  }

  const u16* wl0 = wlds + (size_t)lane * WSTR;
  const u16* wl1 = wlds + (size_t)(64 + lane) * WSTR;
  // producer u64 slot (sans buffer-parity term); valid for tid<128, uo even
  const size_t pstore = (size_t)G * 4096 + (size_t)(ib >> 4) * 1024
                      + (size_t)((ib >> 2) & 3) * 256 + (size_t)(uo >> 1) * 64
                      + (size_t)((ib & 3) * 16 + r_loc);
  // packed slot lines: line (G*4 + w) holds words for blocks ib = 16w..16w+16
  u32* postp = slots + (size_t)(G * 4 + (ib >> 4)) * 16 + (ib & 15);
  const u32* pollp = slots + (size_t)(G * 4 + wave) * 16 + (lane & 15);

  for (int t = 1; t <= NT; ++t) {
    const u32 need = (u32)(t - 1);

    // ---- early poll issue: OLDEST VMEM this iteration; its wait (after X)
    //      does not wait on the emb prefetch (in-order vmcnt retirement) ----
    u32 pv0 = 0;
    if (t > 1)
      pv0 = __hip_atomic_load(pollp, __ATOMIC_RELAXED, __HIP_MEMORY_SCOPE_AGENT);

    // ---- split this step's emb slice (shared by both col-groups) ----
    bfrag8 xh[2], xl[2];
#pragma unroll
    for (int xt = 0; xt < 2; ++xt)
#pragma unroll
      for (int i = 0; i < 4; ++i) {
        u16 h, l;
        split1(xa[xt][i], h, l); xh[xt][i] = (short)h;     xl[xt][i] = (short)l;
        split1(xb[xt][i], h, l); xh[xt][4 + i] = (short)h; xl[xt][4 + i] = (short)l;
      }

    // ---- emb prefetch t+1 (drains under this step's MFMAs/waits) ----
    if (t < NT) {
      int widx = arow * NT + t;
      int wd = is64 ? words[2 * widx] : words[widx];
      const float* xs = emb + (size_t)wd * NE + wave * 64 + koff;
      xa[0] = *(const f32x4*)(xs);      xb[0] = *(const f32x4*)(xs + 4);
      xa[1] = *(const f32x4*)(xs + 32); xb[1] = *(const f32x4*)(xs + 36);
    }

    f32x4 acc0 = {0.f, 0.f, 0.f, 0.f};
    f32x4 acc1 = {0.f, 0.f, 0.f, 0.f};

    // ---- X MFMAs for this wave's k-slice (covers producer lag + poll RT) ----
#pragma unroll
    for (int xt = 0; xt < 2; ++xt) {
      int f = 2 * wave + xt;
      bfrag8 wih = *(const bfrag8*)(wl0 + (32 + f) * 8);
      bfrag8 wil = *(const bfrag8*)(wl0 + (40 + f) * 8);
      acc0 = __builtin_amdgcn_mfma_f32_16x16x32_bf16(xh[xt], wih, acc0, 0, 0, 0);
      acc0 = __builtin_amdgcn_mfma_f32_16x16x32_bf16(xl[xt], wih, acc0, 0, 0, 0);
      acc0 = __builtin_amdgcn_mfma_f32_16x16x32_bf16(xh[xt], wil, acc0, 0, 0, 0);
    }
#pragma unroll
    for (int xt = 0; xt < 2; ++xt) {
      int f = 2 * wave + xt;
      bfrag8 wih = *(const bfrag8*)(wl1 + (32 + f) * 8);
      bfrag8 wil = *(const bfrag8*)(wl1 + (40 + f) * 8);
      acc1 = __builtin_amdgcn_mfma_f32_16x16x32_bf16(xh[xt], wih, acc1, 0, 0, 0);
      acc1 = __builtin_amdgcn_mfma_f32_16x16x32_bf16(xl[xt], wih, acc1, 0, 0, 0);
      acc1 = __builtin_amdgcn_mfma_f32_16x16x32_bf16(xh[xt], wil, acc1, 0, 0, 0);
    }

    // ---- h phase: fast-path check of the early sample; fall back to the
    //      unchanged r12 poll loop; then 16 dense u64 loads ----
    if (t > 1) {
      if (!__all((int)(pv0 >= need))) {
        u32 v;
        do {
          v = __hip_atomic_load(pollp, __ATOMIC_RELAXED, __HIP_MEMORY_SCOPE_AGENT);
        } while (!__all((int)(v >= need)));
      }
      asm volatile("" ::: "memory");        // compiler fence: loads stay below

      const u64* hb = hbuf + ((size_t)(((t - 1) & 1) * 16 + G * 4 + wave)) * 1024 + lane;
      u64 q[16];
#pragma unroll
      for (int i = 0; i < 16; ++i)
        q[i] = __hip_atomic_load(hb + (size_t)i * 64, __ATOMIC_RELAXED, __HIP_MEMORY_SCOPE_AGENT);

#pragma unroll
      for (int ktl = 0; ktl < 4; ++ktl) {
        bfrag8 ah, al;
#pragma unroll
        for (int p = 0; p < 4; ++p) {
          u64 vq = q[ktl * 4 + p];
          u32 w0 = (u32)vq, w1 = (u32)(vq >> 32);
          ah[2 * p]     = (short)(w0 >> 16); al[2 * p]     = (short)(w0 & 0xffffu);
          ah[2 * p + 1] = (short)(w1 >> 16); al[2 * p + 1] = (short)(w1 & 0xffffu);
        }
        int f = 4 * wave + ktl;
        bfrag8 whh0 = *(const bfrag8*)(wl0 + f * 8);
        bfrag8 whl0 = *(const bfrag8*)(wl0 + (16 + f) * 8);
        bfrag8 whh1 = *(const bfrag8*)(wl1 + f * 8);
        bfrag8 whl1 = *(const bfrag8*)(wl1 + (16 + f) * 8);
        acc0 = __builtin_amdgcn_mfma_f32_16x16x32_bf16(ah, whh0, acc0, 0, 0, 0);
        acc1 = __builtin_amdgcn_mfma_f32_16x16x32_bf16(ah, whh1, acc1, 0, 0, 0);
        acc0 = __builtin_amdgcn_mfma_f32_16x16x32_bf16(al, whh0, acc0, 0, 0, 0);
        acc1 = __builtin_amdgcn_mfma_f32_16x16x32_bf16(al, whh1, acc1, 0, 0, 0);
        acc0 = __builtin_amdgcn_mfma_f32_16x16x32_bf16(ah, whl0, acc0, 0, 0, 0);
        acc1 = __builtin_amdgcn_mfma_f32_16x16x32_bf16(ah, whl1, acc1, 0, 0, 0);
      }
    }

    // ---- write K-partials to LDS ----
    {
      int rb = (lane >> 4) << 2;
#pragma unroll
      for (int r = 0; r < 4; ++r) {
        pl[(wave * 16 + rb + r) * 34 + colq] = acc0[r];
        pl[(wave * 16 + rb + r) * 34 + 16 + colq] = acc1[r];
      }
    }
    __syncthreads();                        // sync1: partials visible

    // ---- K-reduce + gate math: thread (r_loc, uo) owns unit 8ib+uo ----
    if (tid < 128) {
      int clb = ((uo >> 2) << 4) + (uo & 3);
      const float* pr = pl + r_loc * 34;
      float xr = biasLds[clb], xf = biasLds[clb + 4];
      float xg = biasLds[clb + 8], xo = biasLds[clb + 12];
#pragma unroll
      for (int w = 0; w < 4; ++w) {
        const float* pw = pr + w * 16 * 34;
        xr += pw[clb]; xf += pw[clb + 4]; xg += pw[clb + 8]; xo += pw[clb + 12];
      }
      float rg = fsigm(xr), fg = fsigm(xf), gg = ftanh(xg), og = fsigm(xo);
      creg = fg * creg + rg * gg;
      float hv = og * ftanh(creg);
      u16 hhi, hlo; split1(hv, hhi, hlo);
      u32 hval = ((u32)hhi << 16) | (u32)hlo;
      u32 pv = (u32)__shfl_xor((int)hval, 1);   // partner unit (uo^1)
      int grow = 16 * G + r_loc;
      int gcol = 8 * ib + uo;
      if ((uo & 1) == 0) {
        u64 e = (u64)hval | ((u64)pv << 32);
        __hip_atomic_store(hbuf + (size_t)(t & 1) * 16384 + pstore, e,
                           __ATOMIC_RELAXED, __HIP_MEMORY_SCOPE_AGENT);
        u32 hspack = (u32)hhi | (pv & 0xffff0000u);
        *(u32*)&hs_all[(size_t)(t - 1) * (NB * NH) + (size_t)grow * NH + gcol] = hspack;
      }
      if (t == NT) hlast[grow * NH + gcol] = hv;
    }

    // ---- sync2: implicit per-wave vmcnt(0) drains h stores, then post ----
    __syncthreads();
    if (tid == 0)
      __hip_atomic_store(postp, (u32)t, __ATOMIC_RELAXED, __HIP_MEMORY_SCOPE_AGENT);
  }
}

// ---------------- attention + output head (one WG per batch, 512 thr) -------
__global__ __launch_bounds__(512) void post_kernel(
    const float* __restrict__ hlast,  // [B][H] fp32
    const u16* __restrict__ hs,       // [T][B][H] bf16
    const float* __restrict__ W_ol, const float* __restrict__ b_ol,   // [256][512], [256]
    const float* __restrict__ W_att, const float* __restrict__ b_att, // [256][512], [512]
    const float* __restrict__ W_fc, const float* __restrict__ b_fc,   // [2][768], [2]
    float* __restrict__ out)          // [64*2] ++ [64*512] fp32
{
  int b = blockIdx.x, tid = threadIdx.x;
  __shared__ float hl[NH], fh[256], sc[NH], att[NT], ao[NH], red[512];
  __shared__ u16 rowbuf[32 * 520];   // 32 hs rows staged; stride 520 u16

  {
    int i = tid;                     // 512 threads cover NH=512 exactly
    float hv = hlast[b * NH + i];
    hl[i] = hv;
    out[128 + b * NH + i] = hv;      // output 1: h_last
  }
  __syncthreads();

  // final_hidden[j] = b_ol[j] + hl . W_ol[j][:]   (j = tid < 256)
  if (tid < 256) {
    float s = b_ol[tid];
    const float* w = W_ol + (size_t)tid * NH;
    for (int k = 0; k < NH; k += 4) {
      f32x4 q = *(const f32x4*)(w + k);
      s += q[0] * hl[k] + q[1] * hl[k + 1] + q[2] * hl[k + 2] + q[3] * hl[k + 3];
    }
    fh[tid] = s;
  }
  __syncthreads();

  // score[h] = b_att[h] + sum_j fh[j] * W_att[j][h]   (h = tid)
  {
    int h = tid;
    float s = b_att[h];
    for (int j = 0; j < 256; ++j) s += fh[j] * W_att[(size_t)j * NH + h];
    sc[h] = s;
  }
  __syncthreads();

  // att[t] = score . hs[t][b][:] -- LDS-staged tiles of 32 rows:
  // coalesced global loads, 16 threads/row dot, 4-step shfl reduce.
  {
    int r = tid >> 4, p = tid & 15;
    for (int t0 = 0; t0 < NT; t0 += 32) {
      const u16* src = hs + ((size_t)(t0 + r) * NB + b) * NH + p * 32;
      uint4 v0 = *(const uint4*)(src);
      uint4 v1 = *(const uint4*)(src + 8);
      uint4 v2 = *(const uint4*)(src + 16);
      uint4 v3 = *(const uint4*)(src + 24);
      u16* dst = rowbuf + r * 520 + p * 32;
      *(uint4*)(dst) = v0; *(uint4*)(dst + 8) = v1;
      *(uint4*)(dst + 16) = v2; *(uint4*)(dst + 24) = v3;
      __syncthreads();
      const u16* row = rowbuf + r * 520 + p * 32;
      float s = 0.f;
      for (int k = 0; k < 32; k += 8) {
        uint4 qv = *(const uint4*)(row + k);
        float tmp[8]; unpack8(qv, tmp);
        const float* scv = &sc[p * 32 + k];
#pragma unroll
        for (int j = 0; j < 8; ++j) s += tmp[j] * scv[j];
      }
      s += __shfl_xor(s, 1); s += __shfl_xor(s, 2);
      s += __shfl_xor(s, 4); s += __shfl_xor(s, 8);
      if (p == 0) att[t0 + r] = s;
      __syncthreads();
    }
  }

  // softmax over T (one value per thread)
  float l0 = att[tid];
  red[tid] = l0;
  __syncthreads();
  for (int s = 256; s > 0; s >>= 1) { if (tid < s) red[tid] = fmaxf(red[tid], red[tid + s]); __syncthreads(); }
  float mx = red[0];
  __syncthreads();
  float e0 = __expf(l0 - mx);
  red[tid] = e0;
  __syncthreads();
  for (int s = 256; s > 0; s >>= 1) { if (tid < s) red[tid] += red[tid + s]; __syncthreads(); }
  float inv = 1.0f / red[0];
  __syncthreads();
  att[tid] = e0 * inv;
  __syncthreads();

  // att_out[h] = sum_t dist[t] * hs[t][b][h]   (h = tid; coalesced)
  {
    float a0 = 0.f;
    for (int t = 0; t < NT; ++t)
      a0 += att[t] * bf2f(hs[((size_t)t * NB + b) * NH + tid]);
    ao[tid] = a0;
  }
  __syncthreads();

  // out[o] = sigmoid(b_fc[o] + [fh, ao] . W_fc[o][:])
#pragma unroll
  for (int o = 0; o < 2; ++o) {
    float part = 0.f;
    for (int i = tid; i < 768; i += 512) {
      float v = (i < 256) ? fh[i] : ao[i - 256];
      part += v * W_fc[o * 768 + i];
    }
    red[tid] = part;
    __syncthreads();
    for (int s = 256; s > 0; s >>= 1) { if (tid < s) red[tid] += red[tid + s]; __syncthreads(); }
    if (tid == 0) out[b * 2 + o] = fsigm(red[0] + b_fc[o]);
    __syncthreads();
  }
}

// ---------------- host launch: memset(slots) + persist + post ---------------
extern "C" void kernel_launch(void* const* d_in, const int* in_sizes, int n_in,
                              void* d_out, int out_size, void* d_ws, size_t ws_size,
                              hipStream_t stream) {
  const int* words  = (const int*)d_in[0];
  const float* emb  = (const float*)d_in[1];
  const float* Wir  = (const float*)d_in[2];  const float* bir = (const float*)d_in[3];
  const float* Whr  = (const float*)d_in[4];  const float* bhr = (const float*)d_in[5];
  const float* Wif  = (const float*)d_in[6];  const float* bif = (const float*)d_in[7];
  const float* Whf  = (const float*)d_in[8];  const float* bhf = (const float*)d_in[9];
  const float* Wig  = (const float*)d_in[10]; const float* big_ = (const float*)d_in[11];
  const float* Whg  = (const float*)d_in[12]; const float* bhg = (const float*)d_in[13];
  const float* Wio  = (const float*)d_in[14]; const float* bio = (const float*)d_in[15];
  const float* Who  = (const float*)d_in[16]; const float* bho = (const float*)d_in[17];
  const float* W_att = (const float*)d_in[18]; const float* b_att = (const float*)d_in[19];
  const float* W_ol  = (const float*)d_in[20]; const float* b_ol  = (const float*)d_in[21];
  const float* W_fc  = (const float*)d_in[22]; const float* b_fc  = (const float*)d_in[23];

  uint8_t* ws = (uint8_t*)d_ws;
  u16* hs       = (u16*)ws;                              // 512*64*512*2 = 32 MiB
  size_t off    = (size_t)33554432;
  u64* hbuf     = (u64*)(ws + off);   off += 262144;     // 2*16384 u64 = 256KB
  float* hlast  = (float*)(ws + off); off += 131072;     // 64*512*4
  u32* slots    = (u32*)(ws + off);                      // 16 packed 64B lines

  hipMemsetAsync(slots, 0, 1024, stream);                // reset per launch/replay

  lstm_persist<<<dim3(NBLK), dim3(256), 0, stream>>>(
      words, emb,
      Whr, Whf, Whg, Who, Wir, Wif, Wig, Wio,
      bhr, bhf, bhg, bho, bir, bif, big_, bio,
      hbuf, hs, hlast, slots);

  post_kernel<<<dim3(NB), dim3(512), 0, stream>>>(hlast, hs, W_ol, b_ol, W_att, b_att,
                                                  W_fc, b_fc, (float*)d_out);
}

// Round 14
// 1592.416 us; speedup vs baseline: 1.4047x; 1.4047x over previous
//
#include <hip/hip_runtime.h>
#include <cstdint>
#include <cstddef>

typedef unsigned short u16;
typedef unsigned int u32;
typedef unsigned long long u64;
typedef __attribute__((ext_vector_type(8))) short bfrag8;   // 8 bf16 = 4 VGPRs
typedef __attribute__((ext_vector_type(4))) float f32x4;

#define NB 64      // batch
#define NT 512     // timesteps
#define NE 256     // embedding dim
#define NH 512     // hidden dim
#define NBLK 256   // persistent blocks: 4 batch-groups x 64 col-blocks
#define WSTR 408   // wlds per-lane stride in u16

__device__ __forceinline__ float bf2f(u16 b) { return __uint_as_float(((unsigned)b) << 16); }
__device__ __forceinline__ u16 f2bf(float f) {
  unsigned u = __float_as_uint(f);
  u += 0x7fffu + ((u >> 16) & 1u);   // round-to-nearest-even
  return (u16)(u >> 16);
}
__device__ __forceinline__ float fsigm(float x) { return 1.0f / (1.0f + __expf(-x)); }
__device__ __forceinline__ float ftanh(float x) { return 2.0f / (1.0f + __expf(-2.0f * x)) - 1.0f; }

// split fp32 -> (hi, lo) bf16 pair; hi + lo == v to ~2^-18 relative
__device__ __forceinline__ void split1(float v, u16& h, u16& l) {
  h = f2bf(v);
  float r = v - bf2f(h);
  l = f2bf(r);
}
__device__ __forceinline__ void split8(const float* p, bfrag8& hi, bfrag8& lo) {
#pragma unroll
  for (int i = 0; i < 8; ++i) {
    u16 h, l; split1(p[i], h, l);
    hi[i] = (short)h; lo[i] = (short)l;
  }
}

__device__ __forceinline__ void unpack8(uint4 q, float* o) {
  o[0] = __uint_as_float(q.x << 16); o[1] = __uint_as_float(q.x & 0xffff0000u);
  o[2] = __uint_as_float(q.y << 16); o[3] = __uint_as_float(q.y & 0xffff0000u);
  o[4] = __uint_as_float(q.z << 16); o[5] = __uint_as_float(q.z & 0xffff0000u);
  o[6] = __uint_as_float(q.w << 16); o[7] = __uint_as_float(q.w & 0xffff0000u);
}

// ---------------- persistent LSTM: 256 blocks = 4 batch-groups x 64 ----------
// Best verified configuration (r10 protocol + r12 fused staging):
//  * packed slot lines -- wave w polls ONE 64B line slotline[G][w] word
//    (ib&15); producer posts after sync2's implicit vmcnt(0) drain
//  * 4-wave K-split, LDS partial reduce, gate math on tid<128
//  * weight staging fused into the prologue (no separate dispatch, no wbuf)
__global__ __launch_bounds__(256, 1) void lstm_persist(
    const int* __restrict__ words,
    const float* __restrict__ emb,
    const float* __restrict__ Whr, const float* __restrict__ Whf,
    const float* __restrict__ Whg, const float* __restrict__ Who,
    const float* __restrict__ Wir, const float* __restrict__ Wif,
    const float* __restrict__ Wig, const float* __restrict__ Wio,
    const float* __restrict__ bhr, const float* __restrict__ bhf,
    const float* __restrict__ bhg, const float* __restrict__ bho,
    const float* __restrict__ bir, const float* __restrict__ bif,
    const float* __restrict__ big_, const float* __restrict__ bio,
    u64* __restrict__ hbuf,     // [2][4][4][4][4][64] u64 fragment-major
    u16* __restrict__ hs_all,   // [T][B][H] bf16 (attention path, cached)
    float* __restrict__ hlast,  // [B][H] fp32 final h
    u32* __restrict__ slots)    // [4 groups][4 waves][16 words] packed lines
{
  const int G    = blockIdx.x >> 6;         // batch group 0..3
  const int ib   = blockIdx.x & 63;         // col-block 0..63
  const int tid  = threadIdx.x;
  const int lane = tid & 63;
  const int wave = tid >> 6;                // K-slice 0..3
  const int colq = lane & 15;
  const int koff = (lane >> 4) * 8;
  const int arow = 16 * G + colq;           // batch row for A fragments

  __shared__ u16 wlds[2 * 64 * WSTR];       // ~102KB weights (2 col-groups)
  __shared__ float pl[4 * 16 * 34];         // K-partials [w][row][32+pad]
  __shared__ float biasLds[32];

  // ---- fused weight staging: identical image to the old stage_weights ----
  if (wave < 2) {
    const int wg2  = ib * 2 + wave;         // old staging-wg index
    const int gate = colq >> 2;
    const int gu   = wg2 * 4 + (colq & 3);
    const float* wh = (gate == 0) ? Whr : (gate == 1) ? Whf : (gate == 2) ? Whg : Who;
    const float* wi = (gate == 0) ? Wir : (gate == 1) ? Wif : (gate == 2) ? Wig : Wio;
    const float* whp = wh + (size_t)gu * NH + koff;
    const float* wip = wi + (size_t)gu * NE + koff;
    u16* dst = wlds + (size_t)(wave * 64 + lane) * WSTR;
#pragma unroll
    for (int kt = 0; kt < 16; ++kt) {
      bfrag8 hi, lo; split8(whp + kt * 32, hi, lo);
      *(bfrag8*)(dst + kt * 8) = hi;
      *(bfrag8*)(dst + (16 + kt) * 8) = lo;
    }
#pragma unroll
    for (int kt = 0; kt < 8; ++kt) {
      bfrag8 hi, lo; split8(wip + kt * 32, hi, lo);
      *(bfrag8*)(dst + (32 + kt) * 8) = hi;
      *(bfrag8*)(dst + (40 + kt) * 8) = lo;
    }
  }
  if (tid < 32) {
    int wg2 = ib * 2 + (tid >> 4), l = tid & 15;
    int g2 = l >> 2, u2 = l & 3, gu2 = wg2 * 4 + u2;
    const float* bh = (g2 == 0) ? bhr : (g2 == 1) ? bhf : (g2 == 2) ? bhg : bho;
    const float* bi = (g2 == 0) ? bir : (g2 == 1) ? bif : (g2 == 2) ? big_ : bio;
    biasLds[tid] = bh[gu2] + bi[gu2];
  }
  __syncthreads();

  const bool is64 = ((words[1] | words[3] | words[5] | words[7]) == 0);
  const int r_loc = tid >> 3;               // gate-phase row (tid<128)
  const int uo    = tid & 7;                // gate-phase unit offset
  float creg = 0.0f;                        // one cell state per gate thread

  // preamble: emb gather for t=1 (wave w loads its X k-slice only)
  f32x4 xa[2], xb[2];
  {
    int widx = arow * NT + 0;
    int wd = is64 ? words[2 * widx] : words[widx];
    const float* xs = emb + (size_t)wd * NE + wave * 64 + koff;
    xa[0] = *(const f32x4*)(xs);      xb[0] = *(const f32x4*)(xs + 4);
    xa[1] = *(const f32x4*)(xs + 32); xb[1] = *(const f32x4*)(xs + 36);
  }

  const u16* wl0 = wlds + (size_t)lane * WSTR;
  const u16* wl1 = wlds + (size_t)(64 + lane) * WSTR;
  // producer u64 slot (sans buffer-parity term); valid for tid<128, uo even
  const size_t pstore = (size_t)G * 4096 + (size_t)(ib >> 4) * 1024
                      + (size_t)((ib >> 2) & 3) * 256 + (size_t)(uo >> 1) * 64
                      + (size_t)((ib & 3) * 16 + r_loc);
  // packed slot lines: line (G*4 + w) holds words for blocks ib = 16w..16w+16
  u32* postp = slots + (size_t)(G * 4 + (ib >> 4)) * 16 + (ib & 15);
  const u32* pollp = slots + (size_t)(G * 4 + wave) * 16 + (lane & 15);

  for (int t = 1; t <= NT; ++t) {
    // ---- split this step's emb slice (shared by both col-groups) ----
    bfrag8 xh[2], xl[2];
#pragma unroll
    for (int xt = 0; xt < 2; ++xt)
#pragma unroll
      for (int i = 0; i < 4; ++i) {
        u16 h, l;
        split1(xa[xt][i], h, l); xh[xt][i] = (short)h;     xl[xt][i] = (short)l;
        split1(xb[xt][i], h, l); xh[xt][4 + i] = (short)h; xl[xt][4 + i] = (short)l;
      }

    // ---- emb prefetch t+1 (drains under this step's MFMAs/waits) ----
    if (t < NT) {
      int widx = arow * NT + t;
      int wd = is64 ? words[2 * widx] : words[widx];
      const float* xs = emb + (size_t)wd * NE + wave * 64 + koff;
      xa[0] = *(const f32x4*)(xs);      xb[0] = *(const f32x4*)(xs + 4);
      xa[1] = *(const f32x4*)(xs + 32); xb[1] = *(const f32x4*)(xs + 36);
    }

    f32x4 acc0 = {0.f, 0.f, 0.f, 0.f};
    f32x4 acc1 = {0.f, 0.f, 0.f, 0.f};

    // ---- X MFMAs for this wave's k-slice (covers producer lag) ----
#pragma unroll
    for (int xt = 0; xt < 2; ++xt) {
      int f = 2 * wave + xt;
      bfrag8 wih = *(const bfrag8*)(wl0 + (32 + f) * 8);
      bfrag8 wil = *(const bfrag8*)(wl0 + (40 + f) * 8);
      acc0 = __builtin_amdgcn_mfma_f32_16x16x32_bf16(xh[xt], wih, acc0, 0, 0, 0);
      acc0 = __builtin_amdgcn_mfma_f32_16x16x32_bf16(xl[xt], wih, acc0, 0, 0, 0);
      acc0 = __builtin_amdgcn_mfma_f32_16x16x32_bf16(xh[xt], wil, acc0, 0, 0, 0);
    }
#pragma unroll
    for (int xt = 0; xt < 2; ++xt) {
      int f = 2 * wave + xt;
      bfrag8 wih = *(const bfrag8*)(wl1 + (32 + f) * 8);
      bfrag8 wil = *(const bfrag8*)(wl1 + (40 + f) * 8);
      acc1 = __builtin_amdgcn_mfma_f32_16x16x32_bf16(xh[xt], wih, acc1, 0, 0, 0);
      acc1 = __builtin_amdgcn_mfma_f32_16x16x32_bf16(xl[xt], wih, acc1, 0, 0, 0);
      acc1 = __builtin_amdgcn_mfma_f32_16x16x32_bf16(xh[xt], wil, acc1, 0, 0, 0);
    }

    // ---- h phase: poll my packed slot line, then 16 dense u64 loads ----
    if (t > 1) {
      const u32 need = (u32)(t - 1);
      u32 v;
      do {
        v = __hip_atomic_load(pollp, __ATOMIC_RELAXED, __HIP_MEMORY_SCOPE_AGENT);
      } while (!__all((int)(v >= need)));
      asm volatile("" ::: "memory");        // compiler fence: loads stay below

      const u64* hb = hbuf + ((size_t)(((t - 1) & 1) * 16 + G * 4 + wave)) * 1024 + lane;
      u64 q[16];
#pragma unroll
      for (int i = 0; i < 16; ++i)
        q[i] = __hip_atomic_load(hb + (size_t)i * 64, __ATOMIC_RELAXED, __HIP_MEMORY_SCOPE_AGENT);

#pragma unroll
      for (int ktl = 0; ktl < 4; ++ktl) {
        bfrag8 ah, al;
#pragma unroll
        for (int p = 0; p < 4; ++p) {
          u64 vq = q[ktl * 4 + p];
          u32 w0 = (u32)vq, w1 = (u32)(vq >> 32);
          ah[2 * p]     = (short)(w0 >> 16); al[2 * p]     = (short)(w0 & 0xffffu);
          ah[2 * p + 1] = (short)(w1 >> 16); al[2 * p + 1] = (short)(w1 & 0xffffu);
        }
        int f = 4 * wave + ktl;
        bfrag8 whh0 = *(const bfrag8*)(wl0 + f * 8);
        bfrag8 whl0 = *(const bfrag8*)(wl0 + (16 + f) * 8);
        bfrag8 whh1 = *(const bfrag8*)(wl1 + f * 8);
        bfrag8 whl1 = *(const bfrag8*)(wl1 + (16 + f) * 8);
        acc0 = __builtin_amdgcn_mfma_f32_16x16x32_bf16(ah, whh0, acc0, 0, 0, 0);
        acc1 = __builtin_amdgcn_mfma_f32_16x16x32_bf16(ah, whh1, acc1, 0, 0, 0);
        acc0 = __builtin_amdgcn_mfma_f32_16x16x32_bf16(al, whh0, acc0, 0, 0, 0);
        acc1 = __builtin_amdgcn_mfma_f32_16x16x32_bf16(al, whh1, acc1, 0, 0, 0);
        acc0 = __builtin_amdgcn_mfma_f32_16x16x32_bf16(ah, whl0, acc0, 0, 0, 0);
        acc1 = __builtin_amdgcn_mfma_f32_16x16x32_bf16(ah, whl1, acc1, 0, 0, 0);
      }
    }

    // ---- write K-partials to LDS ----
    {
      int rb = (lane >> 4) << 2;
#pragma unroll
      for (int r = 0; r < 4; ++r) {
        pl[(wave * 16 + rb + r) * 34 + colq] = acc0[r];
        pl[(wave * 16 + rb + r) * 34 + 16 + colq] = acc1[r];
      }
    }
    __syncthreads();                        // sync1: partials visible

    // ---- K-reduce + gate math: thread (r_loc, uo) owns unit 8ib+uo ----
    if (tid < 128) {
      int clb = ((uo >> 2) << 4) + (uo & 3);
      const float* pr = pl + r_loc * 34;
      float xr = biasLds[clb], xf = biasLds[clb + 4];
      float xg = biasLds[clb + 8], xo = biasLds[clb + 12];
#pragma unroll
      for (int w = 0; w < 4; ++w) {
        const float* pw = pr + w * 16 * 34;
        xr += pw[clb]; xf += pw[clb + 4]; xg += pw[clb + 8]; xo += pw[clb + 12];
      }
      float rg = fsigm(xr), fg = fsigm(xf), gg = ftanh(xg), og = fsigm(xo);
      creg = fg * creg + rg * gg;
      float hv = og * ftanh(creg);
      u16 hhi, hlo; split1(hv, hhi, hlo);
      u32 hval = ((u32)hhi << 16) | (u32)hlo;
      u32 pv = (u32)__shfl_xor((int)hval, 1);   // partner unit (uo^1)
      int grow = 16 * G + r_loc;
      int gcol = 8 * ib + uo;
      if ((uo & 1) == 0) {
        u64 e = (u64)hval | ((u64)pv << 32);
        __hip_atomic_store(hbuf + (size_t)(t & 1) * 16384 + pstore, e,
                           __ATOMIC_RELAXED, __HIP_MEMORY_SCOPE_AGENT);
        u32 hspack = (u32)hhi | (pv & 0xffff0000u);
        *(u32*)&hs_all[(size_t)(t - 1) * (NB * NH) + (size_t)grow * NH + gcol] = hspack;
      }
      if (t == NT) hlast[grow * NH + gcol] = hv;
    }

    // ---- sync2: implicit per-wave vmcnt(0) drains h stores, then post ----
    __syncthreads();
    if (tid == 0)
      __hip_atomic_store(postp, (u32)t, __ATOMIC_RELAXED, __HIP_MEMORY_SCOPE_AGENT);
  }
}

// ---------------- attention + output head (one WG per batch) ----------------
__global__ __launch_bounds__(256) void post_kernel(
    const float* __restrict__ hlast,  // [B][H] fp32
    const u16* __restrict__ hs,       // [T][B][H] bf16
    const float* __restrict__ W_ol, const float* __restrict__ b_ol,   // [256][512], [256]
    const float* __restrict__ W_att, const float* __restrict__ b_att, // [256][512], [512]
    const float* __restrict__ W_fc, const float* __restrict__ b_fc,   // [2][768], [2]
    float* __restrict__ out)          // [64*2] ++ [64*512] fp32
{
  int b = blockIdx.x, tid = threadIdx.x;
  __shared__ float hl[NH], fh[256], sc[NH], att[NT], ao[NH], red[256];
  __shared__ u16 rowbuf[16 * 520];   // 16 hs rows staged; stride 520 u16

  for (int i = tid; i < NH; i += 256) {
    float hv = hlast[b * NH + i];
    hl[i] = hv;
    out[128 + b * NH + i] = hv;   // output 1: h_last
  }
  __syncthreads();

  // final_hidden[j] = b_ol[j] + hl . W_ol[j][:]
  {
    float s = b_ol[tid];
    const float* w = W_ol + (size_t)tid * NH;
    for (int k = 0; k < NH; k += 4) {
      f32x4 q = *(const f32x4*)(w + k);
      s += q[0] * hl[k] + q[1] * hl[k + 1] + q[2] * hl[k + 2] + q[3] * hl[k + 3];
    }
    fh[tid] = s;
  }
  __syncthreads();

  // score[h] = b_att[h] + sum_j fh[j] * W_att[j][h]
  for (int h = tid; h < NH; h += 256) {
    float s = b_att[h];
    for (int j = 0; j < 256; ++j) s += fh[j] * W_att[(size_t)j * NH + h];
    sc[h] = s;
  }
  __syncthreads();

  // att[t] = score . hs[t][b][:] -- LDS-staged tiles of 16 rows:
  // coalesced global loads, 16 threads/row dot, 4-step shfl reduce.
  {
    int r = tid >> 4, p = tid & 15;
    for (int t0 = 0; t0 < NT; t0 += 16) {
      const u16* src = hs + ((size_t)(t0 + r) * NB + b) * NH + p * 32;
      uint4 v0 = *(const uint4*)(src);
      uint4 v1 = *(const uint4*)(src + 8);
      uint4 v2 = *(const uint4*)(src + 16);
      uint4 v3 = *(const uint4*)(src + 24);
      u16* dst = rowbuf + r * 520 + p * 32;
      *(uint4*)(dst) = v0; *(uint4*)(dst + 8) = v1;
      *(uint4*)(dst + 16) = v2; *(uint4*)(dst + 24) = v3;
      __syncthreads();
      const u16* row = rowbuf + r * 520 + p * 32;
      float s = 0.f;
      for (int k = 0; k < 32; k += 8) {
        uint4 qv = *(const uint4*)(row + k);
        float tmp[8]; unpack8(qv, tmp);
        const float* scv = &sc[p * 32 + k];
#pragma unroll
        for (int j = 0; j < 8; ++j) s += tmp[j] * scv[j];
      }
      s += __shfl_xor(s, 1); s += __shfl_xor(s, 2);
      s += __shfl_xor(s, 4); s += __shfl_xor(s, 8);
      if (p == 0) att[t0 + r] = s;
      __syncthreads();
    }
  }

  // softmax over T
  float l0 = att[tid], l1 = att[tid + 256];
  red[tid] = fmaxf(l0, l1);
  __syncthreads();
  for (int s = 128; s > 0; s >>= 1) { if (tid < s) red[tid] = fmaxf(red[tid], red[tid + s]); __syncthreads(); }
  float mx = red[0];
  __syncthreads();
  float e0 = __expf(l0 - mx), e1 = __expf(l1 - mx);
  red[tid] = e0 + e1;
  __syncthreads();
  for (int s = 128; s > 0; s >>= 1) { if (tid < s) red[tid] += red[tid + s]; __syncthreads(); }
  float inv = 1.0f / red[0];
  __syncthreads();
  att[tid] = e0 * inv;
  att[tid + 256] = e1 * inv;
  __syncthreads();

  // att_out[h] = sum_t dist[t] * hs[t][b][h]   (coalesced: lanes span h)
  {
    float a0 = 0.f, a1 = 0.f;
    for (int t = 0; t < NT; ++t) {
      float d = att[t];
      const u16* row = hs + ((size_t)t * NB + b) * NH;
      a0 += d * bf2f(row[tid]);
      a1 += d * bf2f(row[tid + 256]);
    }
    ao[tid] = a0;
    ao[tid + 256] = a1;
  }
  __syncthreads();

  // out[o] = sigmoid(b_fc[o] + [fh, ao] . W_fc[o][:])
#pragma unroll
  for (int o = 0; o < 2; ++o) {
    float part = 0.f;
    for (int i = tid; i < 768; i += 256) {
      float v = (i < 256) ? fh[i] : ao[i - 256];
      part += v * W_fc[o * 768 + i];
    }
    red[tid] = part;
    __syncthreads();
    for (int s = 128; s > 0; s >>= 1) { if (tid < s) red[tid] += red[tid + s]; __syncthreads(); }
    if (tid == 0) out[b * 2 + o] = fsigm(red[0] + b_fc[o]);
    __syncthreads();
  }
}

// ---------------- host launch: memset(slots) + persist + post ---------------
extern "C" void kernel_launch(void* const* d_in, const int* in_sizes, int n_in,
                              void* d_out, int out_size, void* d_ws, size_t ws_size,
                              hipStream_t stream) {
  const int* words  = (const int*)d_in[0];
  const float* emb  = (const float*)d_in[1];
  const float* Wir  = (const float*)d_in[2];  const float* bir = (const float*)d_in[3];
  const float* Whr  = (const float*)d_in[4];  const float* bhr = (const float*)d_in[5];
  const float* Wif  = (const float*)d_in[6];  const float* bif = (const float*)d_in[7];
  const float* Whf  = (const float*)d_in[8];  const float* bhf = (const float*)d_in[9];
  const float* Wig  = (const float*)d_in[10]; const float* big_ = (const float*)d_in[11];
  const float* Whg  = (const float*)d_in[12]; const float* bhg = (const float*)d_in[13];
  const float* Wio  = (const float*)d_in[14]; const float* bio = (const float*)d_in[15];
  const float* Who  = (const float*)d_in[16]; const float* bho = (const float*)d_in[17];
  const float* W_att = (const float*)d_in[18]; const float* b_att = (const float*)d_in[19];
  const float* W_ol  = (const float*)d_in[20]; const float* b_ol  = (const float*)d_in[21];
  const float* W_fc  = (const float*)d_in[22]; const float* b_fc  = (const float*)d_in[23];

  uint8_t* ws = (uint8_t*)d_ws;
  u16* hs       = (u16*)ws;                              // 512*64*512*2 = 32 MiB
  size_t off    = (size_t)33554432;
  u64* hbuf     = (u64*)(ws + off);   off += 262144;     // 2*16384 u64 = 256KB
  float* hlast  = (float*)(ws + off); off += 131072;     // 64*512*4
  u32* slots    = (u32*)(ws + off);                      // 16 packed 64B lines

  hipMemsetAsync(slots, 0, 1024, stream);                // reset per launch/replay

  lstm_persist<<<dim3(NBLK), dim3(256), 0, stream>>>(
      words, emb,
      Whr, Whf, Whg, Who, Wir, Wif, Wig, Wio,
      bhr, bhf, bhg, bho, bir, bif, big_, bio,
      hbuf, hs, hlast, slots);

  post_kernel<<<dim3(NB), dim3(256), 0, stream>>>(hlast, hs, W_ol, b_ol, W_att, b_att,
                                                  W_fc, b_fc, (float*)d_out);
}